// Round 3
// baseline (295.494 us; speedup 1.0000x reference)
//
#include <hip/hip_runtime.h>
#include <hip/hip_bf16.h>

typedef unsigned int u32;
typedef unsigned short ushort_t;
typedef __bf16 bf16x8 __attribute__((ext_vector_type(8)));
typedef float f32x4 __attribute__((ext_vector_type(4)));
typedef unsigned short ushort8 __attribute__((ext_vector_type(8)));

// Problem constants
#define GM 25088          // B*T*14*14
#define GK 768            // CIN*P*P
#define GN 768            // D
#define LDA_PAD 72        // 64 + 8 bf16 pad -> conflict-free ds_read/ds_write

__device__ __forceinline__ ushort_t f2bf(float f) {
    u32 u = __float_as_uint(f);
    u32 r = (u + 0x7FFFu + ((u >> 16) & 1u)) >> 16;
    return (ushort_t)r;
}

__device__ __forceinline__ void load_lds16(const void* g, void* l) {
    __builtin_amdgcn_global_load_lds(
        (const __attribute__((address_space(1))) u32*)g,
        (__attribute__((address_space(3))) u32*)l, 16, 0, 0);
}

// ---------------------------------------------------------------
// Pack proj_w (D, C*P*P) fp32 -> bf16 (same layout = B^T)
// ---------------------------------------------------------------
__global__ __launch_bounds__(256) void pack_w(const float* __restrict__ w,
                                              ushort_t* __restrict__ Wp) {
    size_t g = ((size_t)blockIdx.x * 256 + threadIdx.x) * 8;
    f32x4 f0 = *(const f32x4*)(w + g);
    f32x4 f1 = *(const f32x4*)(w + g + 4);
    ushort8 r;
    r[0] = f2bf(f0[0]); r[1] = f2bf(f0[1]); r[2] = f2bf(f0[2]); r[3] = f2bf(f0[3]);
    r[4] = f2bf(f1[0]); r[5] = f2bf(f1[1]); r[6] = f2bf(f1[2]); r[7] = f2bf(f1[3]);
    *(ushort8*)(Wp + g) = r;
}

// ---------------------------------------------------------------
// Box MLP, d-split for 3x TLP: one block per (b,t,dchunk)
// emb[b][t][o][d] = relu(relu(box/224 @ w1) @ w2)[d] + cats[t][o][d]
// ---------------------------------------------------------------
__global__ __launch_bounds__(256) void box_mlp(const float* __restrict__ meta,
                                               const float* __restrict__ w1,
                                               const float* __restrict__ w2,
                                               const float* __restrict__ cats,
                                               float* __restrict__ emb) {
    int bt = blockIdx.x / 3;
    int dc = blockIdx.x % 3;
    int b = bt / 8, t = bt % 8;
    __shared__ float H[3][384];
    int tid = threadIdx.x;
    for (int idx = tid; idx < 3 * 384; idx += 256) {
        int o = idx / 384, j = idx % 384;
        const float* mp = meta + ((b * 3 + o) * 8 + t) * 4;
        float s = 0.f;
        #pragma unroll
        for (int i = 0; i < 4; ++i) s += (mp[i] * (1.0f / 224.0f)) * w1[i * 384 + j];
        H[o][j] = fmaxf(s, 0.f);
    }
    __syncthreads();
    int d = dc * 256 + tid;
    float acc[3] = {0.f, 0.f, 0.f};
    #pragma unroll 4
    for (int j = 0; j < 384; ++j) {
        float wv = w2[j * 768 + d];
        acc[0] += H[0][j] * wv;
        acc[1] += H[1][j] * wv;
        acc[2] += H[2][j] * wv;
    }
    #pragma unroll
    for (int o = 0; o < 3; ++o) {
        emb[((size_t)bt * 3 + o) * 768 + d] =
            fmaxf(acc[o], 0.f) + cats[(t * 3 + o) * 768 + d];
    }
}

// ---------------------------------------------------------------
// Fused GEMM: C[m][n] = sum_k A[m][k]*Bt[n][k] + pb[n]
// A produced on the fly from x (B,C,T,224,224) fp32 -> bf16 (reg-staged)
// 128x128 tile, BK=64, 4 waves (2x2), mfma_f32_16x16x32_bf16
// C = feat (bt, y, x, d) fp32
// ---------------------------------------------------------------
__global__ __launch_bounds__(256) void gemm_fused(const float* __restrict__ X,
                                                  const ushort_t* __restrict__ Bt,
                                                  const float* __restrict__ pb,
                                                  float* __restrict__ C) {
    __shared__ ushort_t lA[128 * LDA_PAD];
    __shared__ ushort_t lB[128 * 64];
    int tid = threadIdx.x;
    int bm = blockIdx.x % 196;
    int bn = blockIdx.x / 196;
    size_t m0 = (size_t)bm * 128, n0 = (size_t)bn * 128;
    int w = tid >> 6, lane = tid & 63;
    int wr = w >> 1, wc = w & 1;

    // A-staging assignment: thread handles rows (tid>>2) and (tid>>2)+64,
    // p-segment pseg = tid&3 (16 floats each)
    int arow1 = tid >> 2;
    int arow2 = arow1 + 64;
    int pseg = tid & 3;
    int m1 = (int)m0 + arow1;
    int m2 = m1 + 64;
    int w1i = m1 % 14, h1 = (m1 / 14) % 14, t1 = (m1 / 196) % 8, b1 = m1 / 1568;
    int w2i = m2 % 14, h2 = (m2 / 14) % 14, t2 = (m2 / 196) % 8, b2 = m2 / 1568;
    // base of (b,t,h,w) at c=0, p=pseg, q=0
    const float* p1 = X + ((size_t)(b1 * 24 + t1) * 224 + h1 * 16 + pseg) * 224 + w1i * 16;
    const float* p2 = X + ((size_t)(b2 * 24 + t2) * 224 + h2 * 16 + pseg) * 224 + w2i * 16;

    f32x4 xr0, xr1, xr2, xr3, xr4, xr5, xr6, xr7;

    // prefetch kt=0 (c=0, pband=0)
    xr0 = *(const f32x4*)(p1);
    xr1 = *(const f32x4*)(p1 + 4);
    xr2 = *(const f32x4*)(p1 + 8);
    xr3 = *(const f32x4*)(p1 + 12);
    xr4 = *(const f32x4*)(p2);
    xr5 = *(const f32x4*)(p2 + 4);
    xr6 = *(const f32x4*)(p2 + 8);
    xr7 = *(const f32x4*)(p2 + 12);

    f32x4 acc[4][4] = {};

    ushort_t* sA1 = &lA[arow1 * LDA_PAD + pseg * 16];
    ushort_t* sA2 = &lA[arow2 * LDA_PAD + pseg * 16];

    for (int kt = 0; kt < 12; ++kt) {
        int k0 = kt * 64;
        __syncthreads();
        // stage B via global_load_lds (linear layout)
        #pragma unroll
        for (int r = 0; r < 4; ++r) {
            int cidx = r * 256 + tid;
            int row = cidx >> 3;
            int col = (cidx & 7) * 8;
            load_lds16(Bt + ((n0 + row) * 768 + k0 + col), &lB[(size_t)cidx * 8]);
        }
        // convert prefetched A regs -> LDS (conflict-free via LDA_PAD)
        {
            ushort8 u0, u1;
            u0[0] = f2bf(xr0[0]); u0[1] = f2bf(xr0[1]); u0[2] = f2bf(xr0[2]); u0[3] = f2bf(xr0[3]);
            u0[4] = f2bf(xr1[0]); u0[5] = f2bf(xr1[1]); u0[6] = f2bf(xr1[2]); u0[7] = f2bf(xr1[3]);
            u1[0] = f2bf(xr2[0]); u1[1] = f2bf(xr2[1]); u1[2] = f2bf(xr2[2]); u1[3] = f2bf(xr2[3]);
            u1[4] = f2bf(xr3[0]); u1[5] = f2bf(xr3[1]); u1[6] = f2bf(xr3[2]); u1[7] = f2bf(xr3[3]);
            *(ushort8*)(sA1) = u0;
            *(ushort8*)(sA1 + 8) = u1;
            ushort8 u2, u3;
            u2[0] = f2bf(xr4[0]); u2[1] = f2bf(xr4[1]); u2[2] = f2bf(xr4[2]); u2[3] = f2bf(xr4[3]);
            u2[4] = f2bf(xr5[0]); u2[5] = f2bf(xr5[1]); u2[6] = f2bf(xr5[2]); u2[7] = f2bf(xr5[3]);
            u3[0] = f2bf(xr6[0]); u3[1] = f2bf(xr6[1]); u3[2] = f2bf(xr6[2]); u3[3] = f2bf(xr6[3]);
            u3[4] = f2bf(xr7[0]); u3[5] = f2bf(xr7[1]); u3[6] = f2bf(xr7[2]); u3[7] = f2bf(xr7[3]);
            *(ushort8*)(sA2) = u2;
            *(ushort8*)(sA2 + 8) = u3;
        }
        __syncthreads();
        // prefetch next A k-tile during MFMA phase
        if (kt < 11) {
            int ktn = kt + 1;
            size_t off = (size_t)(ktn >> 2) * 401408 + (size_t)(ktn & 3) * 896;
            const float* a1 = p1 + off;
            const float* a2 = p2 + off;
            xr0 = *(const f32x4*)(a1);
            xr1 = *(const f32x4*)(a1 + 4);
            xr2 = *(const f32x4*)(a1 + 8);
            xr3 = *(const f32x4*)(a1 + 12);
            xr4 = *(const f32x4*)(a2);
            xr5 = *(const f32x4*)(a2 + 4);
            xr6 = *(const f32x4*)(a2 + 8);
            xr7 = *(const f32x4*)(a2 + 12);
        }
        #pragma unroll
        for (int kk = 0; kk < 2; ++kk) {
            bf16x8 af[4], bfr[4];
            #pragma unroll
            for (int mi = 0; mi < 4; ++mi)
                af[mi] = *(const bf16x8*)&lA[(wr * 64 + mi * 16 + (lane & 15)) * LDA_PAD
                                             + kk * 32 + (lane >> 4) * 8];
            #pragma unroll
            for (int ni = 0; ni < 4; ++ni)
                bfr[ni] = *(const bf16x8*)&lB[(wc * 64 + ni * 16 + (lane & 15)) * 64
                                              + kk * 32 + (lane >> 4) * 8];
            #pragma unroll
            for (int mi = 0; mi < 4; ++mi)
                #pragma unroll
                for (int ni = 0; ni < 4; ++ni)
                    acc[mi][ni] = __builtin_amdgcn_mfma_f32_16x16x32_bf16(
                        af[mi], bfr[ni], acc[mi][ni], 0, 0, 0);
        }
    }

    int rbase = (lane >> 4) * 4;
    int cl = lane & 15;
    #pragma unroll
    for (int ni = 0; ni < 4; ++ni) {
        size_t col = n0 + wc * 64 + ni * 16 + cl;
        float pbv = pb[col];
        #pragma unroll
        for (int mi = 0; mi < 4; ++mi) {
            size_t row = m0 + wr * 64 + mi * 16 + rbase;
            #pragma unroll
            for (int j = 0; j < 4; ++j) {
                C[(row + j) * 768 + col] = acc[mi][ni][j] + pbv;
            }
        }
    }
}

// ---------------------------------------------------------------
// ROI bilinear crop + emb add + final layout
// out[(b*3+o)][t][i*7+j][d] ; one block per (b,t,o,i), 192 threads (d0=tid*4)
// ---------------------------------------------------------------
__global__ __launch_bounds__(192) void roi_kernel(const float* __restrict__ meta,
                                                  const float* __restrict__ feat,
                                                  const float* __restrict__ emb,
                                                  float* __restrict__ out) {
    int id = blockIdx.x;
    int i = id % 7; id /= 7;
    int o = id % 3; id /= 3;
    int t = id % 8;
    int b = id / 8;

    const float* mp = meta + ((b * 3 + o) * 8 + t) * 4;
    float x1 = mp[0] * (1.f / 16.f);
    float y1 = mp[1] * (1.f / 16.f);
    float x2 = mp[2] * (1.f / 16.f);
    float y2 = mp[3] * (1.f / 16.f);

    float ci = (i + 0.5f) * (1.f / 7.f);
    float yg = y1 + ci * (y2 - y1) - 0.5f;
    float y0f = floorf(yg);
    float wy = yg - y0f;
    int y0 = min(max((int)y0f, 0), 13);
    int y1c = min(y0 + 1, 13);

    int bt = b * 8 + t;
    const float* fbase = feat + (size_t)bt * 196 * 768;
    const float* ep = emb + ((size_t)bt * 3 + o) * 768;

    int d = threadIdx.x * 4;
    f32x4 ev = *(const f32x4*)(ep + d);

    for (int j = 0; j < 7; ++j) {
        float cj = (j + 0.5f) * (1.f / 7.f);
        float xgv = x1 + cj * (x2 - x1) - 0.5f;
        float x0f = floorf(xgv);
        float wx = xgv - x0f;
        int x0 = min(max((int)x0f, 0), 13);
        int x1i = min(x0 + 1, 13);

        f32x4 v00 = *(const f32x4*)(fbase + ((size_t)y0 * 14 + x0) * 768 + d);
        f32x4 v01 = *(const f32x4*)(fbase + ((size_t)y0 * 14 + x1i) * 768 + d);
        f32x4 v10 = *(const f32x4*)(fbase + ((size_t)y1c * 14 + x0) * 768 + d);
        f32x4 v11 = *(const f32x4*)(fbase + ((size_t)y1c * 14 + x1i) * 768 + d);

        float w00 = (1.f - wy) * (1.f - wx);
        float w01 = (1.f - wy) * wx;
        float w10 = wy * (1.f - wx);
        float w11 = wy * wx;

        f32x4 r;
        #pragma unroll
        for (int e = 0; e < 4; ++e)
            r[e] = v00[e] * w00 + v01[e] * w01 + v10[e] * w10 + v11[e] * w11 + ev[e];

        int pp = i * 7 + j;
        *(f32x4*)(out + ((((size_t)(b * 3 + o) * 8 + t) * 49 + pp) * 768 + d)) = r;
    }
}

extern "C" void kernel_launch(void* const* d_in, const int* in_sizes, int n_in,
                              void* d_out, int out_size, void* d_ws, size_t ws_size,
                              hipStream_t stream) {
    const float* x     = (const float*)d_in[0];
    const float* meta  = (const float*)d_in[1];
    const float* projw = (const float*)d_in[2];
    const float* projb = (const float*)d_in[3];
    const float* cats  = (const float*)d_in[4];
    const float* w1    = (const float*)d_in[5];
    const float* w2    = (const float*)d_in[6];
    float* out = (float*)d_out;

    char* ws = (char*)d_ws;
    const size_t szW = (size_t)GN * GK * 2;          //  1,179,648
    const size_t szF = (size_t)GM * GN * 4;          // 77,070,336
    ushort_t* Wp   = (ushort_t*)(ws);
    float*    feat = (float*)(ws + szW);
    float*    emb  = (float*)(ws + szW + szF);

    // 1) pack W: (768*768/8)/256 = 288 blocks
    pack_w<<<288, 256, 0, stream>>>(projw, Wp);
    // 2) box MLP: one block per (b,t,dchunk)
    box_mlp<<<128 * 3, 256, 0, stream>>>(meta, w1, w2, cats, emb);
    // 3) fused pack+GEMM: 196 * 6 tiles
    gemm_fused<<<196 * 6, 256, 0, stream>>>(x, Wp, projb, feat);
    // 4) ROI: one block per (b,t,o,i)
    roi_kernel<<<16 * 8 * 3 * 7, 192, 0, stream>>>(meta, feat, emb, out);
}

// Round 4
// 270.535 us; speedup vs baseline: 1.0923x; 1.0923x over previous
//
#include <hip/hip_runtime.h>
#include <hip/hip_bf16.h>

typedef unsigned int u32;
typedef unsigned short ushort_t;
typedef __bf16 bf16x8 __attribute__((ext_vector_type(8)));
typedef float f32x4 __attribute__((ext_vector_type(4)));
typedef unsigned short ushort8 __attribute__((ext_vector_type(8)));

// Problem constants
#define GM 25088          // B*T*14*14
#define GK 768            // CIN*P*P
#define GN 768            // D

__device__ __forceinline__ ushort_t f2bf(float f) {
    u32 u = __float_as_uint(f);
    u32 r = (u + 0x7FFFu + ((u >> 16) & 1u)) >> 16;
    return (ushort_t)r;
}

__device__ __forceinline__ void load_lds16(const void* g, void* l) {
    __builtin_amdgcn_global_load_lds(
        (const __attribute__((address_space(1))) u32*)g,
        (__attribute__((address_space(3))) u32*)l, 16, 0, 0);
}

// ---------------------------------------------------------------
// Pack x (B,C,T,224,224) fp32 -> A (M,K) bf16, M=(b,t,h,w), K=(c,p,q)
// Thread reads 16 CONTIGUOUS floats (64B, fully coalesced); writes 32B.
// g = (((b*3+c)*8+t)*224 + row)*14 + w   (= x linear / 16)
// ---------------------------------------------------------------
__global__ __launch_bounds__(256) void pack_a(const float* __restrict__ x,
                                              ushort_t* __restrict__ Ap) {
    int g = blockIdx.x * 256 + threadIdx.x;
    int w = g % 14;
    int rowg = g / 14;
    int row = rowg % 224;
    int bct = rowg / 224;
    int t = bct % 8;
    int bc = bct / 8;
    int c = bc % 3;
    int b = bc / 3;
    int p = row & 15;
    int h = row >> 4;
    const float* src = x + (size_t)g * 16;
    f32x4 f0 = *(const f32x4*)src;
    f32x4 f1 = *(const f32x4*)(src + 4);
    f32x4 f2 = *(const f32x4*)(src + 8);
    f32x4 f3 = *(const f32x4*)(src + 12);
    ushort8 r0, r1;
    r0[0] = f2bf(f0[0]); r0[1] = f2bf(f0[1]); r0[2] = f2bf(f0[2]); r0[3] = f2bf(f0[3]);
    r0[4] = f2bf(f1[0]); r0[5] = f2bf(f1[1]); r0[6] = f2bf(f1[2]); r0[7] = f2bf(f1[3]);
    r1[0] = f2bf(f2[0]); r1[1] = f2bf(f2[1]); r1[2] = f2bf(f2[2]); r1[3] = f2bf(f2[3]);
    r1[4] = f2bf(f3[0]); r1[5] = f2bf(f3[1]); r1[6] = f2bf(f3[2]); r1[7] = f2bf(f3[3]);
    int m = ((b * 8 + t) * 14 + h) * 14 + w;
    int k = c * 256 + p * 16;
    *(ushort8*)(Ap + (size_t)m * 768 + k) = r0;
    *(ushort8*)(Ap + (size_t)m * 768 + k + 8) = r1;
}

// ---------------------------------------------------------------
// Pack proj_w (D, C*P*P) fp32 -> bf16 (same layout = B^T)
// ---------------------------------------------------------------
__global__ __launch_bounds__(256) void pack_w(const float* __restrict__ w,
                                              ushort_t* __restrict__ Wp) {
    size_t g = ((size_t)blockIdx.x * 256 + threadIdx.x) * 8;
    f32x4 f0 = *(const f32x4*)(w + g);
    f32x4 f1 = *(const f32x4*)(w + g + 4);
    ushort8 r;
    r[0] = f2bf(f0[0]); r[1] = f2bf(f0[1]); r[2] = f2bf(f0[2]); r[3] = f2bf(f0[3]);
    r[4] = f2bf(f1[0]); r[5] = f2bf(f1[1]); r[6] = f2bf(f1[2]); r[7] = f2bf(f1[3]);
    *(ushort8*)(Wp + g) = r;
}

// ---------------------------------------------------------------
// Box MLP, d-split: one block per (b,t,dchunk)
// ---------------------------------------------------------------
__global__ __launch_bounds__(256) void box_mlp(const float* __restrict__ meta,
                                               const float* __restrict__ w1,
                                               const float* __restrict__ w2,
                                               const float* __restrict__ cats,
                                               float* __restrict__ emb) {
    int bt = blockIdx.x / 3;
    int dc = blockIdx.x % 3;
    int b = bt / 8, t = bt % 8;
    __shared__ float H[3][384];
    int tid = threadIdx.x;
    for (int idx = tid; idx < 3 * 384; idx += 256) {
        int o = idx / 384, j = idx % 384;
        const float* mp = meta + ((b * 3 + o) * 8 + t) * 4;
        float s = 0.f;
        #pragma unroll
        for (int i = 0; i < 4; ++i) s += (mp[i] * (1.0f / 224.0f)) * w1[i * 384 + j];
        H[o][j] = fmaxf(s, 0.f);
    }
    __syncthreads();
    int d = dc * 256 + tid;
    float acc[3] = {0.f, 0.f, 0.f};
    #pragma unroll 4
    for (int j = 0; j < 384; ++j) {
        float wv = w2[j * 768 + d];
        acc[0] += H[0][j] * wv;
        acc[1] += H[1][j] * wv;
        acc[2] += H[2][j] * wv;
    }
    #pragma unroll
    for (int o = 0; o < 3; ++o) {
        emb[((size_t)bt * 3 + o) * 768 + d] =
            fmaxf(acc[o], 0.f) + cats[(t * 3 + o) * 768 + d];
    }
}

// ---------------------------------------------------------------
// GEMM: C[m][n] = sum_k A[m][k] * Bt[n][k] + pb[n]
// 128x128 tile, BK=64, 4 waves (2x2), mfma_f32_16x16x32_bf16
// XCD-chunked swizzle: the 6 bn-tiles of each bm colocate on one XCD.
// ---------------------------------------------------------------
__global__ __launch_bounds__(256) void gemm_bt(const ushort_t* __restrict__ A,
                                               const ushort_t* __restrict__ Bt,
                                               const float* __restrict__ pb,
                                               float* __restrict__ C) {
    __shared__ ushort_t lA[128 * 64];
    __shared__ ushort_t lB[128 * 64];
    int tid = threadIdx.x;
    // grid = 1176 = 8 * 147; round-robin XCD assignment -> chunked work id
    int bid = blockIdx.x;
    int wid = (bid & 7) * 147 + (bid >> 3);
    int bm = wid / 6;
    int bn = wid % 6;
    size_t m0 = (size_t)bm * 128, n0 = (size_t)bn * 128;
    int w = tid >> 6, lane = tid & 63;
    int wr = w >> 1, wc = w & 1;

    f32x4 acc[4][4] = {};

    for (int kt = 0; kt < 12; ++kt) {
        int k0 = kt * 64;
        __syncthreads();
        #pragma unroll
        for (int r = 0; r < 4; ++r) {
            int cidx = r * 256 + tid;
            int row = cidx >> 3;
            int col = (cidx & 7) * 8;
            load_lds16(A + ((m0 + row) * 768 + k0 + col), &lA[(size_t)cidx * 8]);
        }
        #pragma unroll
        for (int r = 0; r < 4; ++r) {
            int cidx = r * 256 + tid;
            int row = cidx >> 3;
            int col = (cidx & 7) * 8;
            load_lds16(Bt + ((n0 + row) * 768 + k0 + col), &lB[(size_t)cidx * 8]);
        }
        __syncthreads();
        #pragma unroll
        for (int kk = 0; kk < 2; ++kk) {
            bf16x8 af[4], bfr[4];
            #pragma unroll
            for (int mi = 0; mi < 4; ++mi)
                af[mi] = *(const bf16x8*)&lA[(wr * 64 + mi * 16 + (lane & 15)) * 64
                                             + kk * 32 + (lane >> 4) * 8];
            #pragma unroll
            for (int ni = 0; ni < 4; ++ni)
                bfr[ni] = *(const bf16x8*)&lB[(wc * 64 + ni * 16 + (lane & 15)) * 64
                                              + kk * 32 + (lane >> 4) * 8];
            #pragma unroll
            for (int mi = 0; mi < 4; ++mi)
                #pragma unroll
                for (int ni = 0; ni < 4; ++ni)
                    acc[mi][ni] = __builtin_amdgcn_mfma_f32_16x16x32_bf16(
                        af[mi], bfr[ni], acc[mi][ni], 0, 0, 0);
        }
    }

    int rbase = (lane >> 4) * 4;
    int cl = lane & 15;
    #pragma unroll
    for (int ni = 0; ni < 4; ++ni) {
        size_t col = n0 + wc * 64 + ni * 16 + cl;
        float pbv = pb[col];
        #pragma unroll
        for (int mi = 0; mi < 4; ++mi) {
            size_t row = m0 + wr * 64 + mi * 16 + rbase;
            #pragma unroll
            for (int j = 0; j < 4; ++j) {
                C[(row + j) * 768 + col] = acc[mi][ni][j] + pbv;
            }
        }
    }
}

// ---------------------------------------------------------------
// ROI bilinear crop + emb add + final layout
// XCD-chunked swizzle: each XCD owns 2 consecutive b's (336 blocks)
// so each feat slab (602 KB per bt) is fetched by exactly one L2.
// ---------------------------------------------------------------
__global__ __launch_bounds__(192) void roi_kernel(const float* __restrict__ meta,
                                                  const float* __restrict__ feat,
                                                  const float* __restrict__ emb,
                                                  float* __restrict__ out) {
    // grid = 2688 = 8 * 336
    int bid = blockIdx.x;
    int wid = (bid & 7) * 336 + (bid >> 3);
    int i = wid % 7; wid /= 7;
    int o = wid % 3; wid /= 3;
    int t = wid % 8;
    int b = wid / 8;

    const float* mp = meta + ((b * 3 + o) * 8 + t) * 4;
    float x1 = mp[0] * (1.f / 16.f);
    float y1 = mp[1] * (1.f / 16.f);
    float x2 = mp[2] * (1.f / 16.f);
    float y2 = mp[3] * (1.f / 16.f);

    float ci = (i + 0.5f) * (1.f / 7.f);
    float yg = y1 + ci * (y2 - y1) - 0.5f;
    float y0f = floorf(yg);
    float wy = yg - y0f;
    int y0 = min(max((int)y0f, 0), 13);
    int y1c = min(y0 + 1, 13);

    int bt = b * 8 + t;
    const float* fbase = feat + (size_t)bt * 196 * 768;
    const float* ep = emb + ((size_t)bt * 3 + o) * 768;

    int d = threadIdx.x * 4;
    f32x4 ev = *(const f32x4*)(ep + d);

    for (int j = 0; j < 7; ++j) {
        float cj = (j + 0.5f) * (1.f / 7.f);
        float xgv = x1 + cj * (x2 - x1) - 0.5f;
        float x0f = floorf(xgv);
        float wx = xgv - x0f;
        int x0 = min(max((int)x0f, 0), 13);
        int x1i = min(x0 + 1, 13);

        f32x4 v00 = *(const f32x4*)(fbase + ((size_t)y0 * 14 + x0) * 768 + d);
        f32x4 v01 = *(const f32x4*)(fbase + ((size_t)y0 * 14 + x1i) * 768 + d);
        f32x4 v10 = *(const f32x4*)(fbase + ((size_t)y1c * 14 + x0) * 768 + d);
        f32x4 v11 = *(const f32x4*)(fbase + ((size_t)y1c * 14 + x1i) * 768 + d);

        float w00 = (1.f - wy) * (1.f - wx);
        float w01 = (1.f - wy) * wx;
        float w10 = wy * (1.f - wx);
        float w11 = wy * wx;

        f32x4 r;
        #pragma unroll
        for (int e = 0; e < 4; ++e)
            r[e] = v00[e] * w00 + v01[e] * w01 + v10[e] * w10 + v11[e] * w11 + ev[e];

        int pp = i * 7 + j;
        *(f32x4*)(out + ((((size_t)(b * 3 + o) * 8 + t) * 49 + pp) * 768 + d)) = r;
    }
}

extern "C" void kernel_launch(void* const* d_in, const int* in_sizes, int n_in,
                              void* d_out, int out_size, void* d_ws, size_t ws_size,
                              hipStream_t stream) {
    const float* x     = (const float*)d_in[0];
    const float* meta  = (const float*)d_in[1];
    const float* projw = (const float*)d_in[2];
    const float* projb = (const float*)d_in[3];
    const float* cats  = (const float*)d_in[4];
    const float* w1    = (const float*)d_in[5];
    const float* w2    = (const float*)d_in[6];
    float* out = (float*)d_out;

    char* ws = (char*)d_ws;
    const size_t szA = (size_t)GM * GK * 2;          // 38,535,168
    const size_t szW = (size_t)GN * GK * 2;          //  1,179,648
    const size_t szF = (size_t)GM * GN * 4;          // 77,070,336
    ushort_t* Ap   = (ushort_t*)(ws);
    ushort_t* Wp   = (ushort_t*)(ws + szA);
    float*    feat = (float*)(ws + szA + szW);
    float*    emb  = (float*)(ws + szA + szW + szF);

    // 1) pack A: 25088*48/256 = 4704 blocks (contiguous 64B reads)
    pack_a<<<4704, 256, 0, stream>>>(x, Ap);
    // 2) pack W
    pack_w<<<288, 256, 0, stream>>>(projw, Wp);
    // 3) box MLP
    box_mlp<<<128 * 3, 256, 0, stream>>>(meta, w1, w2, cats, emb);
    // 4) GEMM: 196*6 = 1176 blocks, XCD-chunked
    gemm_bt<<<1176, 256, 0, stream>>>(Ap, Wp, projb, feat);
    // 5) ROI: 2688 blocks, XCD-chunked
    roi_kernel<<<2688, 192, 0, stream>>>(meta, feat, emb, out);
}

// Round 5
// 245.488 us; speedup vs baseline: 1.2037x; 1.1020x over previous
//
#include <hip/hip_runtime.h>
#include <hip/hip_bf16.h>

typedef unsigned int u32;
typedef unsigned short ushort_t;
typedef __bf16 bf16x8 __attribute__((ext_vector_type(8)));
typedef float f32x4 __attribute__((ext_vector_type(4)));
typedef unsigned short ushort8 __attribute__((ext_vector_type(8)));
typedef unsigned short ushort4v __attribute__((ext_vector_type(4)));

// Problem constants
#define GM 25088          // B*T*14*14
#define GK 768            // CIN*P*P
#define GN 768            // D

__device__ __forceinline__ ushort_t f2bf(float f) {
    u32 u = __float_as_uint(f);
    u32 r = (u + 0x7FFFu + ((u >> 16) & 1u)) >> 16;
    return (ushort_t)r;
}

__device__ __forceinline__ f32x4 bf2f4(ushort4v u) {
    f32x4 f;
    #pragma unroll
    for (int e = 0; e < 4; ++e) f[e] = __uint_as_float(((u32)u[e]) << 16);
    return f;
}

__device__ __forceinline__ void load_lds16(const void* g, void* l) {
    __builtin_amdgcn_global_load_lds(
        (const __attribute__((address_space(1))) u32*)g,
        (__attribute__((address_space(3))) u32*)l, 16, 0, 0);
}

// ---------------------------------------------------------------
// prep: fused pack_a + pack_w + box_mlp
//  blocks [0,1176): pack_a — x (B,C,T,224,224) f32 -> Ap (M,768) bf16,
//    XOR-swizzled within each 128B k-band (byte b -> b ^ ((m&7)<<4)).
//    Thread = (m, piece): reads 4x64B (stride 896B), writes 128B contiguous.
//  blocks [1176,1212): pack_w — proj_w -> Wp bf16, same swizzle on n.
//  blocks [1212,1596): box_mlp (b,t,dchunk)
// ---------------------------------------------------------------
__global__ __launch_bounds__(256) void prep(const float* __restrict__ x,
                                            const float* __restrict__ projw,
                                            const float* __restrict__ meta,
                                            const float* __restrict__ w1,
                                            const float* __restrict__ w2,
                                            const float* __restrict__ cats,
                                            ushort_t* __restrict__ Ap,
                                            ushort_t* __restrict__ Wp,
                                            float* __restrict__ emb) {
    __shared__ float H[3][384];
    int bid = blockIdx.x;
    int tid = threadIdx.x;
    if (bid < 1176) {
        int g = bid * 256 + tid;            // [0, 301056)
        int m = g / 12;
        int piece = g % 12;
        int w = m % 14, h = (m / 14) % 14, t = (m / 196) % 8, b = m / 1568;
        int c = piece >> 2, p0 = (piece & 3) * 4;
        const float* src = x + ((size_t)((b * 3 + c) * 8 + t) * 224 + h * 16 + p0) * 224 + w * 16;
        int xo = (m & 7) << 4;              // byte xor within 128B band
        ushort_t* dst = Ap + (size_t)m * 768 + piece * 64;
        #pragma unroll
        for (int i = 0; i < 4; ++i) {
            const float* s = src + i * 224;
            f32x4 f0 = *(const f32x4*)(s);
            f32x4 f1 = *(const f32x4*)(s + 4);
            f32x4 f2 = *(const f32x4*)(s + 8);
            f32x4 f3 = *(const f32x4*)(s + 12);
            ushort8 r0, r1;
            r0[0] = f2bf(f0[0]); r0[1] = f2bf(f0[1]); r0[2] = f2bf(f0[2]); r0[3] = f2bf(f0[3]);
            r0[4] = f2bf(f1[0]); r0[5] = f2bf(f1[1]); r0[6] = f2bf(f1[2]); r0[7] = f2bf(f1[3]);
            r1[0] = f2bf(f2[0]); r1[1] = f2bf(f2[1]); r1[2] = f2bf(f2[2]); r1[3] = f2bf(f2[3]);
            r1[4] = f2bf(f3[0]); r1[5] = f2bf(f3[1]); r1[6] = f2bf(f3[2]); r1[7] = f2bf(f3[3]);
            int b0 = (i * 32) ^ xo;
            int b1 = (i * 32 + 16) ^ xo;
            *(ushort8*)(dst + (b0 >> 1)) = r0;
            *(ushort8*)(dst + (b1 >> 1)) = r1;
        }
    } else if (bid < 1212) {
        int g = (bid - 1176) * 256 + tid;   // [0, 9216)
        int n = g / 12;
        int piece = g % 12;
        const float* src = projw + (size_t)n * 768 + piece * 64;
        int xo = (n & 7) << 4;
        ushort_t* dst = Wp + (size_t)n * 768 + piece * 64;
        #pragma unroll
        for (int i = 0; i < 4; ++i) {
            const float* s = src + i * 16;
            f32x4 f0 = *(const f32x4*)(s);
            f32x4 f1 = *(const f32x4*)(s + 4);
            f32x4 f2 = *(const f32x4*)(s + 8);
            f32x4 f3 = *(const f32x4*)(s + 12);
            ushort8 r0, r1;
            r0[0] = f2bf(f0[0]); r0[1] = f2bf(f0[1]); r0[2] = f2bf(f0[2]); r0[3] = f2bf(f0[3]);
            r0[4] = f2bf(f1[0]); r0[5] = f2bf(f1[1]); r0[6] = f2bf(f1[2]); r0[7] = f2bf(f1[3]);
            r1[0] = f2bf(f2[0]); r1[1] = f2bf(f2[1]); r1[2] = f2bf(f2[2]); r1[3] = f2bf(f2[3]);
            r1[4] = f2bf(f3[0]); r1[5] = f2bf(f3[1]); r1[6] = f2bf(f3[2]); r1[7] = f2bf(f3[3]);
            int b0 = (i * 32) ^ xo;
            int b1 = (i * 32 + 16) ^ xo;
            *(ushort8*)(dst + (b0 >> 1)) = r0;
            *(ushort8*)(dst + (b1 >> 1)) = r1;
        }
    } else {
        int bb = bid - 1212;
        int bt = bb / 3;
        int dc = bb % 3;
        int b = bt / 8, t = bt % 8;
        for (int idx = tid; idx < 3 * 384; idx += 256) {
            int o = idx / 384, j = idx % 384;
            const float* mp = meta + ((b * 3 + o) * 8 + t) * 4;
            float s = 0.f;
            #pragma unroll
            for (int i = 0; i < 4; ++i) s += (mp[i] * (1.0f / 224.0f)) * w1[i * 384 + j];
            H[o][j] = fmaxf(s, 0.f);
        }
        __syncthreads();
        int d = dc * 256 + tid;
        float acc[3] = {0.f, 0.f, 0.f};
        #pragma unroll 4
        for (int j = 0; j < 384; ++j) {
            float wv = w2[j * 768 + d];
            acc[0] += H[0][j] * wv;
            acc[1] += H[1][j] * wv;
            acc[2] += H[2][j] * wv;
        }
        #pragma unroll
        for (int o = 0; o < 3; ++o) {
            emb[((size_t)bt * 3 + o) * 768 + d] =
                fmaxf(acc[o], 0.f) + cats[(t * 3 + o) * 768 + d];
        }
    }
}

// ---------------------------------------------------------------
// GEMM: Cb[m][n] = bf16( sum_k A[m][k]*Bt[n][k] + pb[n] )
// 128x128 tile, BK=64, 4 waves (2x2), double-buffered LDS (T3-min),
// pre-swizzled operands (T2), one barrier per K-step.
// ---------------------------------------------------------------
__global__ __launch_bounds__(256) void gemm_bt(const ushort_t* __restrict__ A,
                                               const ushort_t* __restrict__ Bt,
                                               const float* __restrict__ pb,
                                               ushort_t* __restrict__ Cb) {
    __shared__ ushort_t lA[2][128 * 64];
    __shared__ ushort_t lB[2][128 * 64];
    int tid = threadIdx.x;
    // grid = 1176 = 8 * 147; XCD-chunked work id
    int bid = blockIdx.x;
    int wid = (bid & 7) * 147 + (bid >> 3);
    int bm = wid / 6;
    int bn = wid % 6;
    size_t m0 = (size_t)bm * 128, n0 = (size_t)bn * 128;
    int w = tid >> 6, lane = tid & 63;
    int wr = w >> 1, wc = w & 1;
    int r15 = lane & 15;
    int xoU = (lane & 7) << 3;          // swizzle XOR in ushort units

    f32x4 acc[4][4] = {};

    #define STAGE(buf, kt_)                                                        \
        {                                                                          \
            int k0_ = (kt_) * 64;                                                  \
            _Pragma("unroll")                                                      \
            for (int r = 0; r < 4; ++r) {                                          \
                int cidx = r * 256 + tid;                                          \
                int row = cidx >> 3;                                               \
                int col = (cidx & 7) * 8;                                          \
                load_lds16(A + ((m0 + row) * 768 + k0_ + col), &lA[buf][cidx * 8]);\
            }                                                                      \
            _Pragma("unroll")                                                      \
            for (int r = 0; r < 4; ++r) {                                          \
                int cidx = r * 256 + tid;                                          \
                int row = cidx >> 3;                                               \
                int col = (cidx & 7) * 8;                                          \
                load_lds16(Bt + ((n0 + row) * 768 + k0_ + col), &lB[buf][cidx * 8]);\
            }                                                                      \
        }

    STAGE(0, 0);
    __syncthreads();                    // full drain: buffer 0 ready

    for (int kt = 0; kt < 12; ++kt) {
        int cur = kt & 1;
        if (kt < 11) STAGE(cur ^ 1, kt + 1);   // prefetch next tile into other buffer
        #pragma unroll
        for (int kk = 0; kk < 2; ++kk) {
            int cs = (kk * 32 + (lane >> 4) * 8) ^ xoU;   // swizzled k-offset (ushorts)
            bf16x8 af[4], bfr[4];
            #pragma unroll
            for (int mi = 0; mi < 4; ++mi)
                af[mi] = *(const bf16x8*)&lA[cur][(wr * 64 + mi * 16 + r15) * 64 + cs];
            #pragma unroll
            for (int ni = 0; ni < 4; ++ni)
                bfr[ni] = *(const bf16x8*)&lB[cur][(wc * 64 + ni * 16 + r15) * 64 + cs];
            #pragma unroll
            for (int mi = 0; mi < 4; ++mi)
                #pragma unroll
                for (int ni = 0; ni < 4; ++ni)
                    acc[mi][ni] = __builtin_amdgcn_mfma_f32_16x16x32_bf16(
                        af[mi], bfr[ni], acc[mi][ni], 0, 0, 0);
        }
        __syncthreads();                // drains stage loads (vmcnt 0) + readers done
    }
    #undef STAGE

    int rbase = (lane >> 4) * 4;
    #pragma unroll
    for (int ni = 0; ni < 4; ++ni) {
        size_t col = n0 + wc * 64 + ni * 16 + r15;
        float pbv = pb[col];
        #pragma unroll
        for (int mi = 0; mi < 4; ++mi) {
            size_t row = m0 + wr * 64 + mi * 16 + rbase;
            #pragma unroll
            for (int j = 0; j < 4; ++j) {
                Cb[(row + j) * 768 + col] = f2bf(acc[mi][ni][j] + pbv);
            }
        }
    }
}

// ---------------------------------------------------------------
// ROI bilinear crop + emb add + final layout. feat is bf16.
// grid = 768 blocks (XCD-chunked grid-stride over 2688 work items)
// keeps each XCD's live feat window ~4-5 slabs (<4MB L2).
// ---------------------------------------------------------------
__global__ __launch_bounds__(192) void roi_kernel(const float* __restrict__ meta,
                                                  const ushort_t* __restrict__ featB,
                                                  const float* __restrict__ emb,
                                                  float* __restrict__ out) {
    int xcd = blockIdx.x & 7;
    int idx = blockIdx.x >> 3;          // 0..95
    int d = threadIdx.x * 4;

    for (int wi = idx; wi < 336; wi += 96) {
        int wid = xcd * 336 + wi;
        int i = wid % 7; int r = wid / 7;
        int o = r % 3; r /= 3;
        int t = r % 8;
        int b = r / 8;

        const float* mp = meta + ((b * 3 + o) * 8 + t) * 4;
        float x1 = mp[0] * (1.f / 16.f);
        float y1 = mp[1] * (1.f / 16.f);
        float x2 = mp[2] * (1.f / 16.f);
        float y2 = mp[3] * (1.f / 16.f);

        float ci = (i + 0.5f) * (1.f / 7.f);
        float yg = y1 + ci * (y2 - y1) - 0.5f;
        float y0f = floorf(yg);
        float wy = yg - y0f;
        int y0 = min(max((int)y0f, 0), 13);
        int y1c = min(y0 + 1, 13);

        int bt = b * 8 + t;
        const ushort_t* fbase = featB + (size_t)bt * 196 * 768;
        const float* ep = emb + ((size_t)bt * 3 + o) * 768;
        f32x4 ev = *(const f32x4*)(ep + d);

        #pragma unroll
        for (int j = 0; j < 7; ++j) {
            float cj = (j + 0.5f) * (1.f / 7.f);
            float xgv = x1 + cj * (x2 - x1) - 0.5f;
            float x0f = floorf(xgv);
            float wx = xgv - x0f;
            int x0 = min(max((int)x0f, 0), 13);
            int x1i = min(x0 + 1, 13);

            f32x4 v00 = bf2f4(*(const ushort4v*)(fbase + ((size_t)y0 * 14 + x0) * 768 + d));
            f32x4 v01 = bf2f4(*(const ushort4v*)(fbase + ((size_t)y0 * 14 + x1i) * 768 + d));
            f32x4 v10 = bf2f4(*(const ushort4v*)(fbase + ((size_t)y1c * 14 + x0) * 768 + d));
            f32x4 v11 = bf2f4(*(const ushort4v*)(fbase + ((size_t)y1c * 14 + x1i) * 768 + d));

            float w00 = (1.f - wy) * (1.f - wx);
            float w01 = (1.f - wy) * wx;
            float w10 = wy * (1.f - wx);
            float w11 = wy * wx;

            f32x4 rr;
            #pragma unroll
            for (int e = 0; e < 4; ++e)
                rr[e] = v00[e] * w00 + v01[e] * w01 + v10[e] * w10 + v11[e] * w11 + ev[e];

            int pp = i * 7 + j;
            *(f32x4*)(out + ((((size_t)(b * 3 + o) * 8 + t) * 49 + pp) * 768 + d)) = rr;
        }
    }
}

extern "C" void kernel_launch(void* const* d_in, const int* in_sizes, int n_in,
                              void* d_out, int out_size, void* d_ws, size_t ws_size,
                              hipStream_t stream) {
    const float* x     = (const float*)d_in[0];
    const float* meta  = (const float*)d_in[1];
    const float* projw = (const float*)d_in[2];
    const float* projb = (const float*)d_in[3];
    const float* cats  = (const float*)d_in[4];
    const float* w1    = (const float*)d_in[5];
    const float* w2    = (const float*)d_in[6];
    float* out = (float*)d_out;

    char* ws = (char*)d_ws;
    const size_t szA  = (size_t)GM * GK * 2;         // 38,535,168 (swizzled bf16 A)
    const size_t szW  = (size_t)GN * GK * 2;         //  1,179,648 (swizzled bf16 W)
    const size_t szFB = (size_t)GM * GN * 2;         // 38,535,168 (bf16 feat)
    ushort_t* Ap    = (ushort_t*)(ws);
    ushort_t* Wp    = (ushort_t*)(ws + szA);
    ushort_t* featB = (ushort_t*)(ws + szA + szW);
    float*    emb   = (float*)(ws + szA + szW + szFB);

    // 1) fused prep: 1176 pack_a + 36 pack_w + 384 box_mlp
    prep<<<1596, 256, 0, stream>>>(x, projw, meta, w1, w2, cats, Ap, Wp, emb);
    // 2) GEMM: 1176 blocks, XCD-chunked, dbuf+swizzle
    gemm_bt<<<1176, 256, 0, stream>>>(Ap, Wp, projb, featB);
    // 3) ROI: 768 blocks, XCD-chunked grid-stride
    roi_kernel<<<768, 192, 0, stream>>>(meta, featB, emb, out);
}

// Round 6
// 243.936 us; speedup vs baseline: 1.2114x; 1.0064x over previous
//
#include <hip/hip_runtime.h>
#include <hip/hip_bf16.h>

typedef unsigned int u32;
typedef unsigned short ushort_t;
typedef __bf16 bf16x8 __attribute__((ext_vector_type(8)));
typedef float f32x4 __attribute__((ext_vector_type(4)));
typedef unsigned short ushort8 __attribute__((ext_vector_type(8)));
typedef unsigned short ushort4v __attribute__((ext_vector_type(4)));

// Problem constants
#define GM 25088          // B*T*14*14
#define GK 768            // CIN*P*P
#define GN 768            // D

__device__ __forceinline__ ushort_t f2bf(float f) {
    u32 u = __float_as_uint(f);
    u32 r = (u + 0x7FFFu + ((u >> 16) & 1u)) >> 16;
    return (ushort_t)r;
}

__device__ __forceinline__ f32x4 bf2f4(ushort4v u) {
    f32x4 f;
    #pragma unroll
    for (int e = 0; e < 4; ++e) f[e] = __uint_as_float(((u32)u[e]) << 16);
    return f;
}

__device__ __forceinline__ ushort8 cvt8(f32x4 f0, f32x4 f1) {
    ushort8 r;
    r[0] = f2bf(f0[0]); r[1] = f2bf(f0[1]); r[2] = f2bf(f0[2]); r[3] = f2bf(f0[3]);
    r[4] = f2bf(f1[0]); r[5] = f2bf(f1[1]); r[6] = f2bf(f1[2]); r[7] = f2bf(f1[3]);
    return r;
}

__device__ __forceinline__ void load_lds16(const void* g, void* l) {
    __builtin_amdgcn_global_load_lds(
        (const __attribute__((address_space(1))) u32*)g,
        (__attribute__((address_space(3))) u32*)l, 16, 0, 0);
}

// ---------------------------------------------------------------
// prep: fused pack_a (LDS-transpose) + pack_w + box_mlp
//  blocks [0,1792): pack_a — one block per (b,t,h) row-band.
//    read x contiguously (3 planes x 16 rows x 224 cols), cvt bf16,
//    LDS [c][p][232], then write Ap rows (m,k) with gemm XOR-swizzle.
//  blocks [1792,1828): pack_w — proj_w -> Wp bf16, same swizzle.
//  blocks [1828,2212): box_mlp (b,t,dchunk)
// ---------------------------------------------------------------
__global__ __launch_bounds__(256) void prep(const float* __restrict__ x,
                                            const float* __restrict__ projw,
                                            const float* __restrict__ meta,
                                            const float* __restrict__ w1,
                                            const float* __restrict__ w2,
                                            const float* __restrict__ cats,
                                            ushort_t* __restrict__ Ap,
                                            ushort_t* __restrict__ Wp,
                                            float* __restrict__ emb) {
    __shared__ ushort_t Lsm[3 * 16 * 232];   // 22272 B
    __shared__ float H[3][384];
    int bid = blockIdx.x;
    int tid = threadIdx.x;
    if (bid < 1792) {
        // ---- pack_a: (b,t,h) row-band ----
        int h = bid % 14;
        int t = (bid / 14) % 8;
        int b = bid / 112;
        // read phase: 1344 chunks of 8 floats (32B), fully coalesced
        for (int chunk = tid; chunk < 1344; chunk += 256) {
            int c = chunk / 448;
            int cc = chunk % 448;
            int p = cc / 28;
            int col0 = (cc % 28) * 8;
            const float* s = x + ((size_t)((b * 3 + c) * 8 + t) * 224 + h * 16 + p) * 224 + col0;
            f32x4 f0 = *(const f32x4*)s;
            f32x4 f1 = *(const f32x4*)(s + 4);
            *(ushort8*)&Lsm[(c * 16 + p) * 232 + col0] = cvt8(f0, f1);
        }
        __syncthreads();
        // write phase: 14 m-rows x 96 chunks of 16B, swizzled-contiguous
        int mbase = ((b * 8 + t) * 14 + h) * 14;
        for (int chunk = tid; chunk < 1344; chunk += 256) {
            int w = chunk / 96;
            int kc = chunk % 96;
            int k0 = kc * 8;
            int c = k0 >> 8;
            int p = (k0 >> 4) & 15;
            int q0 = k0 & 15;
            ushort8 r = *(const ushort8*)&Lsm[(c * 16 + p) * 232 + w * 16 + q0];
            int mm = mbase + w;
            int bytesw = (kc * 16) ^ ((mm & 7) << 4);
            *(ushort8*)(Ap + (size_t)mm * 768 + (bytesw >> 1)) = r;
        }
    } else if (bid < 1828) {
        // ---- pack_w ----
        int g = (bid - 1792) * 256 + tid;   // [0, 9216)
        int n = g / 12;
        int piece = g % 12;
        const float* src = projw + (size_t)n * 768 + piece * 64;
        int xo = (n & 7) << 4;
        ushort_t* dst = Wp + (size_t)n * 768 + piece * 64;
        #pragma unroll
        for (int i = 0; i < 4; ++i) {
            const float* s = src + i * 16;
            f32x4 f0 = *(const f32x4*)(s);
            f32x4 f1 = *(const f32x4*)(s + 4);
            f32x4 f2 = *(const f32x4*)(s + 8);
            f32x4 f3 = *(const f32x4*)(s + 12);
            int b0 = (i * 32) ^ xo;
            int b1 = (i * 32 + 16) ^ xo;
            *(ushort8*)(dst + (b0 >> 1)) = cvt8(f0, f1);
            *(ushort8*)(dst + (b1 >> 1)) = cvt8(f2, f3);
        }
    } else {
        // ---- box_mlp ----
        int bb = bid - 1828;
        int bt = bb / 3;
        int dc = bb % 3;
        int b = bt / 8, t = bt % 8;
        for (int idx = tid; idx < 3 * 384; idx += 256) {
            int o = idx / 384, j = idx % 384;
            const float* mp = meta + ((b * 3 + o) * 8 + t) * 4;
            float s = 0.f;
            #pragma unroll
            for (int i = 0; i < 4; ++i) s += (mp[i] * (1.0f / 224.0f)) * w1[i * 384 + j];
            H[o][j] = fmaxf(s, 0.f);
        }
        __syncthreads();
        int d = dc * 256 + tid;
        float acc[3] = {0.f, 0.f, 0.f};
        #pragma unroll 4
        for (int j = 0; j < 384; ++j) {
            float wv = w2[j * 768 + d];
            acc[0] += H[0][j] * wv;
            acc[1] += H[1][j] * wv;
            acc[2] += H[2][j] * wv;
        }
        #pragma unroll
        for (int o = 0; o < 3; ++o) {
            emb[((size_t)bt * 3 + o) * 768 + d] =
                fmaxf(acc[o], 0.f) + cats[(t * 3 + o) * 768 + d];
        }
    }
}

// ---------------------------------------------------------------
// GEMM: Cb[m][n] = bf16( sum_k A[m][k]*Bt[n][k] + pb[n] )
// 128x128 tile, BK=64, 4 waves (2x2), double-buffered LDS,
// pre-swizzled operands, one barrier per K-step. XCD-chunked.
// ---------------------------------------------------------------
__global__ __launch_bounds__(256) void gemm_bt(const ushort_t* __restrict__ A,
                                               const ushort_t* __restrict__ Bt,
                                               const float* __restrict__ pb,
                                               ushort_t* __restrict__ Cb) {
    __shared__ ushort_t lA[2][128 * 64];
    __shared__ ushort_t lB[2][128 * 64];
    int tid = threadIdx.x;
    int bid = blockIdx.x;
    int wid = (bid & 7) * 147 + (bid >> 3);
    int bm = wid / 6;
    int bn = wid % 6;
    size_t m0 = (size_t)bm * 128, n0 = (size_t)bn * 128;
    int w = tid >> 6, lane = tid & 63;
    int wr = w >> 1, wc = w & 1;
    int r15 = lane & 15;
    int xoU = (lane & 7) << 3;          // swizzle XOR in ushort units

    f32x4 acc[4][4] = {};

    #define STAGE(buf, kt_)                                                        \
        {                                                                          \
            int k0_ = (kt_) * 64;                                                  \
            _Pragma("unroll")                                                      \
            for (int r = 0; r < 4; ++r) {                                          \
                int cidx = r * 256 + tid;                                          \
                int row = cidx >> 3;                                               \
                int col = (cidx & 7) * 8;                                          \
                load_lds16(A + ((m0 + row) * 768 + k0_ + col), &lA[buf][cidx * 8]);\
            }                                                                      \
            _Pragma("unroll")                                                      \
            for (int r = 0; r < 4; ++r) {                                          \
                int cidx = r * 256 + tid;                                          \
                int row = cidx >> 3;                                               \
                int col = (cidx & 7) * 8;                                          \
                load_lds16(Bt + ((n0 + row) * 768 + k0_ + col), &lB[buf][cidx * 8]);\
            }                                                                      \
        }

    STAGE(0, 0);
    __syncthreads();

    for (int kt = 0; kt < 12; ++kt) {
        int cur = kt & 1;
        if (kt < 11) STAGE(cur ^ 1, kt + 1);
        #pragma unroll
        for (int kk = 0; kk < 2; ++kk) {
            int cs = (kk * 32 + (lane >> 4) * 8) ^ xoU;
            bf16x8 af[4], bfr[4];
            #pragma unroll
            for (int mi = 0; mi < 4; ++mi)
                af[mi] = *(const bf16x8*)&lA[cur][(wr * 64 + mi * 16 + r15) * 64 + cs];
            #pragma unroll
            for (int ni = 0; ni < 4; ++ni)
                bfr[ni] = *(const bf16x8*)&lB[cur][(wc * 64 + ni * 16 + r15) * 64 + cs];
            #pragma unroll
            for (int mi = 0; mi < 4; ++mi)
                #pragma unroll
                for (int ni = 0; ni < 4; ++ni)
                    acc[mi][ni] = __builtin_amdgcn_mfma_f32_16x16x32_bf16(
                        af[mi], bfr[ni], acc[mi][ni], 0, 0, 0);
        }
        __syncthreads();
    }
    #undef STAGE

    int rbase = (lane >> 4) * 4;
    #pragma unroll
    for (int ni = 0; ni < 4; ++ni) {
        size_t col = n0 + wc * 64 + ni * 16 + r15;
        float pbv = pb[col];
        #pragma unroll
        for (int mi = 0; mi < 4; ++mi) {
            size_t row = m0 + wr * 64 + mi * 16 + rbase;
            #pragma unroll
            for (int j = 0; j < 4; ++j) {
                Cb[(row + j) * 768 + col] = f2bf(acc[mi][ni][j] + pbv);
            }
        }
    }
}

// ---------------------------------------------------------------
// ROI bilinear crop + emb add + final layout. feat is bf16.
// 2688 blocks (one work item each), XCD-chunked for L2 locality.
// ---------------------------------------------------------------
__global__ __launch_bounds__(192) void roi_kernel(const float* __restrict__ meta,
                                                  const ushort_t* __restrict__ featB,
                                                  const float* __restrict__ emb,
                                                  float* __restrict__ out) {
    int bid = blockIdx.x;               // 2688 = 8*336
    int wid = (bid & 7) * 336 + (bid >> 3);
    int i = wid % 7; int r = wid / 7;
    int o = r % 3; r /= 3;
    int t = r % 8;
    int b = r / 8;
    int d = threadIdx.x * 4;

    const float* mp = meta + ((b * 3 + o) * 8 + t) * 4;
    float x1 = mp[0] * (1.f / 16.f);
    float y1 = mp[1] * (1.f / 16.f);
    float x2 = mp[2] * (1.f / 16.f);
    float y2 = mp[3] * (1.f / 16.f);

    float ci = (i + 0.5f) * (1.f / 7.f);
    float yg = y1 + ci * (y2 - y1) - 0.5f;
    float y0f = floorf(yg);
    float wy = yg - y0f;
    int y0 = min(max((int)y0f, 0), 13);
    int y1c = min(y0 + 1, 13);

    int bt = b * 8 + t;
    const ushort_t* fbase = featB + (size_t)bt * 196 * 768;
    const float* ep = emb + ((size_t)bt * 3 + o) * 768;
    f32x4 ev = *(const f32x4*)(ep + d);

    #pragma unroll
    for (int j = 0; j < 7; ++j) {
        float cj = (j + 0.5f) * (1.f / 7.f);
        float xgv = x1 + cj * (x2 - x1) - 0.5f;
        float x0f = floorf(xgv);
        float wx = xgv - x0f;
        int x0 = min(max((int)x0f, 0), 13);
        int x1i = min(x0 + 1, 13);

        f32x4 v00 = bf2f4(*(const ushort4v*)(fbase + ((size_t)y0 * 14 + x0) * 768 + d));
        f32x4 v01 = bf2f4(*(const ushort4v*)(fbase + ((size_t)y0 * 14 + x1i) * 768 + d));
        f32x4 v10 = bf2f4(*(const ushort4v*)(fbase + ((size_t)y1c * 14 + x0) * 768 + d));
        f32x4 v11 = bf2f4(*(const ushort4v*)(fbase + ((size_t)y1c * 14 + x1i) * 768 + d));

        float w00 = (1.f - wy) * (1.f - wx);
        float w01 = (1.f - wy) * wx;
        float w10 = wy * (1.f - wx);
        float w11 = wy * wx;

        f32x4 rr;
        #pragma unroll
        for (int e = 0; e < 4; ++e)
            rr[e] = v00[e] * w00 + v01[e] * w01 + v10[e] * w10 + v11[e] * w11 + ev[e];

        int pp = i * 7 + j;
        *(f32x4*)(out + ((((size_t)(b * 3 + o) * 8 + t) * 49 + pp) * 768 + d)) = rr;
    }
}

extern "C" void kernel_launch(void* const* d_in, const int* in_sizes, int n_in,
                              void* d_out, int out_size, void* d_ws, size_t ws_size,
                              hipStream_t stream) {
    const float* x     = (const float*)d_in[0];
    const float* meta  = (const float*)d_in[1];
    const float* projw = (const float*)d_in[2];
    const float* projb = (const float*)d_in[3];
    const float* cats  = (const float*)d_in[4];
    const float* w1    = (const float*)d_in[5];
    const float* w2    = (const float*)d_in[6];
    float* out = (float*)d_out;

    char* ws = (char*)d_ws;
    const size_t szA  = (size_t)GM * GK * 2;         // 38,535,168 (swizzled bf16 A)
    const size_t szW  = (size_t)GN * GK * 2;         //  1,179,648 (swizzled bf16 W)
    const size_t szFB = (size_t)GM * GN * 2;         // 38,535,168 (bf16 feat)
    ushort_t* Ap    = (ushort_t*)(ws);
    ushort_t* Wp    = (ushort_t*)(ws + szA);
    ushort_t* featB = (ushort_t*)(ws + szA + szW);
    float*    emb   = (float*)(ws + szA + szW + szFB);

    // 1) fused prep: 1792 pack_a + 36 pack_w + 384 box_mlp
    prep<<<2212, 256, 0, stream>>>(x, projw, meta, w1, w2, cats, Ap, Wp, emb);
    // 2) GEMM: 1176 blocks, XCD-chunked, dbuf+swizzle
    gemm_bt<<<1176, 256, 0, stream>>>(Ap, Wp, projb, featB);
    // 3) ROI: 2688 blocks, XCD-chunked
    roi_kernel<<<2688, 192, 0, stream>>>(meta, featB, emb, out);
}

// Round 7
// 225.840 us; speedup vs baseline: 1.3084x; 1.0801x over previous
//
#include <hip/hip_runtime.h>
#include <hip/hip_bf16.h>

typedef unsigned int u32;
typedef unsigned short ushort_t;
typedef __bf16 bf16x8 __attribute__((ext_vector_type(8)));
typedef float f32x4 __attribute__((ext_vector_type(4)));
typedef unsigned short ushort8 __attribute__((ext_vector_type(8)));
typedef unsigned short ushort4v __attribute__((ext_vector_type(4)));

// Problem constants
#define GM 25088          // B*T*14*14
#define GK 768            // CIN*P*P
#define GN 768            // D

__device__ __forceinline__ ushort_t f2bf(float f) {
    u32 u = __float_as_uint(f);
    u32 r = (u + 0x7FFFu + ((u >> 16) & 1u)) >> 16;
    return (ushort_t)r;
}

__device__ __forceinline__ f32x4 bf2f4(ushort4v u) {
    f32x4 f;
    #pragma unroll
    for (int e = 0; e < 4; ++e) f[e] = __uint_as_float(((u32)u[e]) << 16);
    return f;
}

__device__ __forceinline__ ushort8 cvt8(f32x4 f0, f32x4 f1) {
    ushort8 r;
    r[0] = f2bf(f0[0]); r[1] = f2bf(f0[1]); r[2] = f2bf(f0[2]); r[3] = f2bf(f0[3]);
    r[4] = f2bf(f1[0]); r[5] = f2bf(f1[1]); r[6] = f2bf(f1[2]); r[7] = f2bf(f1[3]);
    return r;
}

__device__ __forceinline__ void load_lds16(const void* g, void* l) {
    __builtin_amdgcn_global_load_lds(
        (const __attribute__((address_space(1))) u32*)g,
        (__attribute__((address_space(3))) u32*)l, 16, 0, 0);
}

// ---------------------------------------------------------------
// pack_a (LDS-transpose): one block per (b,t,h) row-band.
// read x contiguously (3 planes x 16 rows x 224 cols), cvt bf16,
// LDS [c][p][232], write Ap rows (m,k) with gemm XOR-swizzle.
// ---------------------------------------------------------------
__global__ __launch_bounds__(256) void pack_a(const float* __restrict__ x,
                                              ushort_t* __restrict__ Ap) {
    __shared__ ushort_t Lsm[3 * 16 * 232];   // 22272 B
    int bid = blockIdx.x;
    int tid = threadIdx.x;
    int h = bid % 14;
    int t = (bid / 14) % 8;
    int b = bid / 112;
    for (int chunk = tid; chunk < 1344; chunk += 256) {
        int c = chunk / 448;
        int cc = chunk % 448;
        int p = cc / 28;
        int col0 = (cc % 28) * 8;
        const float* s = x + ((size_t)((b * 3 + c) * 8 + t) * 224 + h * 16 + p) * 224 + col0;
        f32x4 f0 = *(const f32x4*)s;
        f32x4 f1 = *(const f32x4*)(s + 4);
        *(ushort8*)&Lsm[(c * 16 + p) * 232 + col0] = cvt8(f0, f1);
    }
    __syncthreads();
    int mbase = ((b * 8 + t) * 14 + h) * 14;
    for (int chunk = tid; chunk < 1344; chunk += 256) {
        int w = chunk / 96;
        int kc = chunk % 96;
        int k0 = kc * 8;
        int c = k0 >> 8;
        int p = (k0 >> 4) & 15;
        int q0 = k0 & 15;
        ushort8 r = *(const ushort8*)&Lsm[(c * 16 + p) * 232 + w * 16 + q0];
        int mm = mbase + w;
        int bytesw = (kc * 16) ^ ((mm & 7) << 4);
        *(ushort8*)(Ap + (size_t)mm * 768 + (bytesw >> 1)) = r;
    }
}

// ---------------------------------------------------------------
// pack_w: proj_w (D, 768) f32 -> Wp bf16, XOR-swizzled per n-row
// ---------------------------------------------------------------
__global__ __launch_bounds__(256) void pack_w(const float* __restrict__ projw,
                                              ushort_t* __restrict__ Wp) {
    int g = blockIdx.x * 256 + threadIdx.x;   // [0, 9216)
    int n = g / 12;
    int piece = g % 12;
    const float* src = projw + (size_t)n * 768 + piece * 64;
    int xo = (n & 7) << 4;
    ushort_t* dst = Wp + (size_t)n * 768 + piece * 64;
    #pragma unroll
    for (int i = 0; i < 4; ++i) {
        const float* s = src + i * 16;
        f32x4 f0 = *(const f32x4*)(s);
        f32x4 f1 = *(const f32x4*)(s + 4);
        f32x4 f2 = *(const f32x4*)(s + 8);
        f32x4 f3 = *(const f32x4*)(s + 12);
        int b0 = (i * 32) ^ xo;
        int b1 = (i * 32 + 16) ^ xo;
        *(ushort8*)(dst + (b0 >> 1)) = cvt8(f0, f1);
        *(ushort8*)(dst + (b1 >> 1)) = cvt8(f2, f3);
    }
}

// ---------------------------------------------------------------
// box_mlp: one block per (b,t,dchunk); 16-wide load batching in j
// ---------------------------------------------------------------
__global__ __launch_bounds__(256) void box_mlp(const float* __restrict__ meta,
                                               const float* __restrict__ w1,
                                               const float* __restrict__ w2,
                                               const float* __restrict__ cats,
                                               float* __restrict__ emb) {
    __shared__ float H[3][384];
    int bt = blockIdx.x / 3;
    int dc = blockIdx.x % 3;
    int b = bt / 8, t = bt % 8;
    int tid = threadIdx.x;
    for (int idx = tid; idx < 3 * 384; idx += 256) {
        int o = idx / 384, j = idx % 384;
        const float* mp = meta + ((b * 3 + o) * 8 + t) * 4;
        float s = 0.f;
        #pragma unroll
        for (int i = 0; i < 4; ++i) s += (mp[i] * (1.0f / 224.0f)) * w1[i * 384 + j];
        H[o][j] = fmaxf(s, 0.f);
    }
    __syncthreads();
    int d = dc * 256 + tid;
    const float* wp = w2 + d;
    float acc0 = 0.f, acc1 = 0.f, acc2 = 0.f;
    #pragma unroll 1
    for (int j0 = 0; j0 < 384; j0 += 16) {
        float wv[16];
        #pragma unroll
        for (int u = 0; u < 16; ++u) wv[u] = wp[(size_t)(j0 + u) * 768];
        #pragma unroll
        for (int u = 0; u < 16; ++u) {
            acc0 += H[0][j0 + u] * wv[u];
            acc1 += H[1][j0 + u] * wv[u];
            acc2 += H[2][j0 + u] * wv[u];
        }
    }
    float a[3] = {acc0, acc1, acc2};
    #pragma unroll
    for (int o = 0; o < 3; ++o) {
        emb[((size_t)bt * 3 + o) * 768 + d] =
            fmaxf(a[o], 0.f) + cats[(t * 3 + o) * 768 + d];
    }
}

// ---------------------------------------------------------------
// GEMM: Cb[m][n] = bf16( sum_k A[m][k]*Bt[n][k] + pb[n] )
// 128x128 tile, BK=64, 4 waves (2x2), SINGLE-buffer 32KB LDS
// (m97 structure, 4 blocks/CU), pre-swizzled operands, XCD-chunked.
// ---------------------------------------------------------------
__global__ __launch_bounds__(256) void gemm_bt(const ushort_t* __restrict__ A,
                                               const ushort_t* __restrict__ Bt,
                                               const float* __restrict__ pb,
                                               ushort_t* __restrict__ Cb) {
    __shared__ ushort_t lA[128 * 64];
    __shared__ ushort_t lB[128 * 64];
    int tid = threadIdx.x;
    int bid = blockIdx.x;
    int wid = (bid & 7) * 147 + (bid >> 3);
    int bm = wid / 6;
    int bn = wid % 6;
    size_t m0 = (size_t)bm * 128, n0 = (size_t)bn * 128;
    int w = tid >> 6, lane = tid & 63;
    int wr = w >> 1, wc = w & 1;
    int r15 = lane & 15;
    int xoU = (lane & 7) << 3;          // swizzle XOR in ushort units

    f32x4 acc[4][4] = {};

    for (int kt = 0; kt < 12; ++kt) {
        int k0 = kt * 64;
        __syncthreads();
        #pragma unroll
        for (int r = 0; r < 4; ++r) {
            int cidx = r * 256 + tid;
            int row = cidx >> 3;
            int col = (cidx & 7) * 8;
            load_lds16(A + ((m0 + row) * 768 + k0 + col), &lA[(size_t)cidx * 8]);
        }
        #pragma unroll
        for (int r = 0; r < 4; ++r) {
            int cidx = r * 256 + tid;
            int row = cidx >> 3;
            int col = (cidx & 7) * 8;
            load_lds16(Bt + ((n0 + row) * 768 + k0 + col), &lB[(size_t)cidx * 8]);
        }
        __syncthreads();
        #pragma unroll
        for (int kk = 0; kk < 2; ++kk) {
            int cs = (kk * 32 + (lane >> 4) * 8) ^ xoU;
            bf16x8 af[4], bfr[4];
            #pragma unroll
            for (int mi = 0; mi < 4; ++mi)
                af[mi] = *(const bf16x8*)&lA[(wr * 64 + mi * 16 + r15) * 64 + cs];
            #pragma unroll
            for (int ni = 0; ni < 4; ++ni)
                bfr[ni] = *(const bf16x8*)&lB[(wc * 64 + ni * 16 + r15) * 64 + cs];
            #pragma unroll
            for (int mi = 0; mi < 4; ++mi)
                #pragma unroll
                for (int ni = 0; ni < 4; ++ni)
                    acc[mi][ni] = __builtin_amdgcn_mfma_f32_16x16x32_bf16(
                        af[mi], bfr[ni], acc[mi][ni], 0, 0, 0);
        }
    }

    int rbase = (lane >> 4) * 4;
    #pragma unroll
    for (int ni = 0; ni < 4; ++ni) {
        size_t col = n0 + wc * 64 + ni * 16 + r15;
        float pbv = pb[col];
        #pragma unroll
        for (int mi = 0; mi < 4; ++mi) {
            size_t row = m0 + wr * 64 + mi * 16 + rbase;
            #pragma unroll
            for (int j = 0; j < 4; ++j) {
                Cb[(row + j) * 768 + col] = f2bf(acc[mi][ni][j] + pbv);
            }
        }
    }
}

// ---------------------------------------------------------------
// ROI bilinear crop + emb add + final layout. feat is bf16.
// 2688 blocks (one work item each), XCD-chunked for L2 locality.
// ---------------------------------------------------------------
__global__ __launch_bounds__(192) void roi_kernel(const float* __restrict__ meta,
                                                  const ushort_t* __restrict__ featB,
                                                  const float* __restrict__ emb,
                                                  float* __restrict__ out) {
    int bid = blockIdx.x;               // 2688 = 8*336
    int wid = (bid & 7) * 336 + (bid >> 3);
    int i = wid % 7; int r = wid / 7;
    int o = r % 3; r /= 3;
    int t = r % 8;
    int b = r / 8;
    int d = threadIdx.x * 4;

    const float* mp = meta + ((b * 3 + o) * 8 + t) * 4;
    float x1 = mp[0] * (1.f / 16.f);
    float y1 = mp[1] * (1.f / 16.f);
    float x2 = mp[2] * (1.f / 16.f);
    float y2 = mp[3] * (1.f / 16.f);

    float ci = (i + 0.5f) * (1.f / 7.f);
    float yg = y1 + ci * (y2 - y1) - 0.5f;
    float y0f = floorf(yg);
    float wy = yg - y0f;
    int y0 = min(max((int)y0f, 0), 13);
    int y1c = min(y0 + 1, 13);

    int bt = b * 8 + t;
    const ushort_t* fbase = featB + (size_t)bt * 196 * 768;
    const float* ep = emb + ((size_t)bt * 3 + o) * 768;
    f32x4 ev = *(const f32x4*)(ep + d);

    #pragma unroll
    for (int j = 0; j < 7; ++j) {
        float cj = (j + 0.5f) * (1.f / 7.f);
        float xgv = x1 + cj * (x2 - x1) - 0.5f;
        float x0f = floorf(xgv);
        float wx = xgv - x0f;
        int x0 = min(max((int)x0f, 0), 13);
        int x1i = min(x0 + 1, 13);

        f32x4 v00 = bf2f4(*(const ushort4v*)(fbase + ((size_t)y0 * 14 + x0) * 768 + d));
        f32x4 v01 = bf2f4(*(const ushort4v*)(fbase + ((size_t)y0 * 14 + x1i) * 768 + d));
        f32x4 v10 = bf2f4(*(const ushort4v*)(fbase + ((size_t)y1c * 14 + x0) * 768 + d));
        f32x4 v11 = bf2f4(*(const ushort4v*)(fbase + ((size_t)y1c * 14 + x1i) * 768 + d));

        float w00 = (1.f - wy) * (1.f - wx);
        float w01 = (1.f - wy) * wx;
        float w10 = wy * (1.f - wx);
        float w11 = wy * wx;

        f32x4 rr;
        #pragma unroll
        for (int e = 0; e < 4; ++e)
            rr[e] = v00[e] * w00 + v01[e] * w01 + v10[e] * w10 + v11[e] * w11 + ev[e];

        int pp = i * 7 + j;
        *(f32x4*)(out + ((((size_t)(b * 3 + o) * 8 + t) * 49 + pp) * 768 + d)) = rr;
    }
}

extern "C" void kernel_launch(void* const* d_in, const int* in_sizes, int n_in,
                              void* d_out, int out_size, void* d_ws, size_t ws_size,
                              hipStream_t stream) {
    const float* x     = (const float*)d_in[0];
    const float* meta  = (const float*)d_in[1];
    const float* projw = (const float*)d_in[2];
    const float* projb = (const float*)d_in[3];
    const float* cats  = (const float*)d_in[4];
    const float* w1    = (const float*)d_in[5];
    const float* w2    = (const float*)d_in[6];
    float* out = (float*)d_out;

    char* ws = (char*)d_ws;
    const size_t szA  = (size_t)GM * GK * 2;         // 38,535,168 (swizzled bf16 A)
    const size_t szW  = (size_t)GN * GK * 2;         //  1,179,648 (swizzled bf16 W)
    const size_t szFB = (size_t)GM * GN * 2;         // 38,535,168 (bf16 feat)
    ushort_t* Ap    = (ushort_t*)(ws);
    ushort_t* Wp    = (ushort_t*)(ws + szA);
    ushort_t* featB = (ushort_t*)(ws + szA + szW);
    float*    emb   = (float*)(ws + szA + szW + szFB);

    // split dispatches for rocprof attribution
    pack_a<<<1792, 256, 0, stream>>>(x, Ap);
    pack_w<<<36, 256, 0, stream>>>(projw, Wp);
    box_mlp<<<384, 256, 0, stream>>>(meta, w1, w2, cats, emb);
    gemm_bt<<<1176, 256, 0, stream>>>(Ap, Wp, projb, featB);
    roi_kernel<<<2688, 192, 0, stream>>>(meta, featB, emb, out);
}